// Round 7
// baseline (369.776 us; speedup 1.0000x reference)
//
#include <hip/hip_runtime.h>
#include <stdint.h>

// B=4, S=2048, E=1024, H=16, D=64. fp32 I/O; bf16 MFMA compute.
// R10: flash = R9's fenced 2-state pipeline x R5's 64-q-rows/wave geometry.
// Cost model (R5-R9 counters): matrix-pipe busy is constant 28-30 us;
// dominant term is LDS READ BW: at 32 q/wave each wave reads the whole
// 32KB K+V tile per kt -> 2.1 GB LDS traffic (~40 us of 85 B/cyc/CU).
// 64 q/wave halves LDS bytes per score: qk2 feeds BOTH q-tiles from one
// ka read; pv2 feeds both from one vb read. Fenced skew keeps matrix
// pipe fed during exp2/cvt_pk (R9's proven mechanism, VGPR tell: 88).
// GEMMs and cvt identical to R9.

typedef unsigned short u16;
typedef __bf16 bf16x8 __attribute__((ext_vector_type(8)));
typedef float f32x4 __attribute__((ext_vector_type(4)));
typedef float f32x16 __attribute__((ext_vector_type(16)));
typedef uint32_t u32x4 __attribute__((ext_vector_type(4)));

#define MFMA_BF16(a, b, c) __builtin_amdgcn_mfma_f32_16x16x32_bf16((a), (b), (c), 0, 0, 0)
#define MFMA32(a, b, c)    __builtin_amdgcn_mfma_f32_32x32x16_bf16((a), (b), (c), 0, 0, 0)
#define GAMMA 0.18033688011112042f   // (1/8) * log2(e): folded into Q projection
#define BHSTRIDE 131072              // 2048 * 64 elems per (b,h) slice
#define FENCE() __builtin_amdgcn_sched_barrier(0)

static __device__ __forceinline__ u16 f2bf(float f) {
    uint32_t u = __builtin_bit_cast(uint32_t, f);
    u = (u + 0x7FFFu + ((u >> 16) & 1u)) >> 16;   // RNE
    return (u16)u;
}

static __device__ __forceinline__ uint32_t pk_rne2(float a, float b) {
    uint32_t ua = __builtin_bit_cast(uint32_t, a);
    uint32_t ub = __builtin_bit_cast(uint32_t, b);
    ua += 0x7FFFu + ((ua >> 16) & 1u);
    ub += 0x7FFFu + ((ub >> 16) & 1u);
    return __builtin_amdgcn_perm(ub, ua, 0x07060302);
}

static __device__ __forceinline__ void async_copy16(const void* g, void* l) {
    __builtin_amdgcn_global_load_lds((__attribute__((address_space(1))) void*)g,
                                     (__attribute__((address_space(3))) void*)l,
                                     16, 0, 0);
}

// raw hardware exp2: exactly one trans instruction, no libm range fixups
static __device__ __forceinline__ float aexp2(float x) {
    float r;
    asm("v_exp_f32 %0, %1" : "=v"(r) : "v"(x));
    return r;
}

// pack two f32 -> one u32 of 2 bf16 (lo=a, hi=b); no builtin on gfx950
static __device__ __forceinline__ uint32_t cvtpk(float a, float b) {
    uint32_t r;
    asm("v_cvt_pk_bf16_f32 %0, %1, %2" : "=v"(r) : "v"(a), "v"(b));
    return r;
}

// exchange a's upper 32 lanes with b's lower 32 lanes (both modified)
static __device__ __forceinline__ void plswap(uint32_t& a, uint32_t& b) {
    asm("v_permlane32_swap_b32 %0, %1" : "+v"(a), "+v"(b));
}

static __device__ __forceinline__ bf16x8 mkfrag(uint32_t w0, uint32_t w1,
                                                uint32_t w2, uint32_t w3) {
    u32x4 u = {w0, w1, w2, w3};
    return __builtin_bit_cast(bf16x8, u);
}

// ---------------------------------------------------------------------------
// fp32 -> bf16 batched converter.
// ---------------------------------------------------------------------------
struct CvtArgs { const float* s[6]; u16* d[6]; };

__global__ __launch_bounds__(256) void cvt_kernel(CvtArgs a, int nelem) {
    const float* s = a.s[blockIdx.z];
    u16* d = a.d[blockIdx.z];
    int i = (blockIdx.x * 256 + threadIdx.x) * 8;
    float4 f0 = *(const float4*)(s + i);
    float4 f1 = *(const float4*)(s + i + 4);
    uint4 w;
    w.x = pk_rne2(f0.x, f0.y); w.y = pk_rne2(f0.z, f0.w);
    w.z = pk_rne2(f1.x, f1.y); w.w = pk_rne2(f1.z, f1.w);
    *(uint4*)(d + i) = w;
}

// ---------------------------------------------------------------------------
// C = scale * sum_p A_p @ W_p^T, bf16, M=8192, N=K=1024, 128x128 tile, BK=64.
// Staging: linear LDS dest (global_load_lds), pre-swizzled global source,
// swizzled ds_read (chunk ^ ((row>>3)^row)&7 within 128B rows).  (R6 version)
// AMODE: 0 = A natural row-major (M x K); 1 = A head-major [bh][s][64].
// CMODE: 0 = fp32 natural; 1 = bf16 head-major [bh][s][64];
//        2 = bf16 transposed head-major [bh][d][s] (packed 4-token stores).
// ---------------------------------------------------------------------------
template <int AMODE, int CMODE>
__global__ __launch_bounds__(256, 2) void gemm_bt(
    const u16* __restrict__ A0, const u16* __restrict__ W0,
    const u16* __restrict__ A1, const u16* __restrict__ W1,
    void* __restrict__ Cv, int K, int npairs, float scale)
{
    __shared__ __align__(16) u16 lA[128 * 64];   // 16 KB
    __shared__ __align__(16) u16 lB[128 * 64];   // 16 KB

    const int tid  = threadIdx.x;
    const int lane = tid & 63;
    const int wave = tid >> 6;
    const int wm   = (wave >> 1) * 64;
    const int wn   = (wave & 1) * 64;
    const size_t m0 = (size_t)blockIdx.x * 128;
    const size_t n0 = (size_t)blockIdx.y * 128;

    const int row8 = tid >> 3;       // 0..31
    const int cp   = tid & 7;        // 16B chunk within 128B row
    const int fr   = lane & 15;
    const int g    = lane >> 4;      // 0..3

    const size_t bb = (m0 >> 11) * 16;   // b*16 (tile never straddles a batch)
    const size_t s0 = m0 & 2047;

    f32x4 acc[4][4] = {};

    for (int p = 0; p < npairs; ++p) {
        const u16* A = p ? A1 : A0;
        const u16* W = p ? W1 : W0;
        for (int k0 = 0; k0 < K; k0 += 64) {
            __syncthreads();
#pragma unroll
            for (int it = 0; it < 4; ++it) {
                int row = it * 32 + row8;
                int sc = cp ^ (((row >> 3) ^ row) & 7);
                if (AMODE == 0) {
                    async_copy16(A + ((m0 + row) * (size_t)K + k0 + sc * 8),
                                 (char*)lA + it * 4096 + tid * 16);
                } else {
                    // head-major: k-step of 64 == exactly one head's D slice
                    size_t base = (bb + (size_t)(k0 >> 6)) * BHSTRIDE;
                    async_copy16(A + base + (s0 + row) * 64 + sc * 8,
                                 (char*)lA + it * 4096 + tid * 16);
                }
                async_copy16(W + ((n0 + row) * (size_t)K + k0 + sc * 8),
                             (char*)lB + it * 4096 + tid * 16);
            }
            __syncthreads();

            bf16x8 af[4][2], bfm[4][2];
#pragma unroll
            for (int i = 0; i < 4; ++i) {
                int row = wm + i * 16 + fr;
                int sw = ((row >> 3) ^ row) & 7;
                af[i][0] = *(const bf16x8*)(lA + row * 64 + (g ^ sw) * 8);
                af[i][1] = *(const bf16x8*)(lA + row * 64 + ((4 + g) ^ sw) * 8);
            }
#pragma unroll
            for (int j = 0; j < 4; ++j) {
                int row = wn + j * 16 + fr;
                int sw = ((row >> 3) ^ row) & 7;
                bfm[j][0] = *(const bf16x8*)(lB + row * 64 + (g ^ sw) * 8);
                bfm[j][1] = *(const bf16x8*)(lB + row * 64 + ((4 + g) ^ sw) * 8);
            }
#pragma unroll
            for (int i = 0; i < 4; ++i)
#pragma unroll
                for (int j = 0; j < 4; ++j) {
                    acc[i][j] = MFMA_BF16(af[i][0], bfm[j][0], acc[i][j]);
                    acc[i][j] = MFMA_BF16(af[i][1], bfm[j][1], acc[i][j]);
                }
        }
    }

#pragma unroll
    for (int i = 0; i < 4; ++i)
#pragma unroll
        for (int j = 0; j < 4; ++j) {
            if (CMODE == 2) {
                size_t row0 = m0 + wm + i * 16 + g * 4;        // 4 consecutive tokens
                size_t col  = n0 + wn + j * 16 + fr;
                size_t addr = ((row0 >> 11) * 16 + (col >> 6)) * BHSTRIDE
                            + (size_t)(col & 63) * 2048 + (row0 & 2047);
                ushort4 pk;
                pk.x = f2bf(acc[i][j][0] * scale);
                pk.y = f2bf(acc[i][j][1] * scale);
                pk.z = f2bf(acc[i][j][2] * scale);
                pk.w = f2bf(acc[i][j][3] * scale);
                *(ushort4*)((u16*)Cv + addr) = pk;
            } else {
#pragma unroll
                for (int rg = 0; rg < 4; ++rg) {
                    size_t row = m0 + wm + i * 16 + g * 4 + rg;
                    size_t col = n0 + wn + j * 16 + fr;
                    float v = acc[i][j][rg] * scale;
                    if (CMODE == 0) {
                        ((float*)Cv)[row * 1024 + col] = v;
                    } else {
                        size_t addr = ((row >> 11) * 16 + (col >> 6)) * BHSTRIDE
                                    + (row & 2047) * 64 + (col & 63);
                        ((u16*)Cv)[addr] = f2bf(v);
                    }
                }
            }
        }
}

// ---------------------------------------------------------------------------
// Flash attention, non-causal, 32x32x16 MFMA, swapped QK^T, in-register P,
// FENCED score pipeline over TWO q-tiles per wave (64 q-rows): one ka read
// feeds both q-tiles' QK MFMAs, one vb read feeds both PV MFMAs -> LDS
// read bytes per score halved vs R9. Per kt (128 keys = 4 chunks):
//   qk2(0) | stage || sm(A0)|qk2(1)|sm(B0)|pv2(0) || sm(A1)|qk2(2)|... 
// Head-major buffers: Q,K,O = [bh][s][64], Vt = [bh][d][s].
// Grid 512 linear, XCD-pinned: xcd=id&7, 8 bh per XCD -> 4 MB K/V in L2.
// 256 threads = 4 waves; wave owns 64 q-rows; block covers 256 q-rows.
// 128-key tiles double-buffered (64 KB LDS) -> 2 blocks/CU.
// Constant-max exp2 softmax (gamma folded into Q projection).
// ---------------------------------------------------------------------------
__global__ __launch_bounds__(256, 2) void flash_kernel(
    const u16* __restrict__ Qhm, const u16* __restrict__ Khm,
    const u16* __restrict__ Vt, u16* __restrict__ Ohm)
{
    __shared__ __align__(16) u16 sK[2][128 * 64];    // 32 KB
    __shared__ __align__(16) u16 sVt[2][64 * 128];   // 32 KB

    const int tid  = threadIdx.x;
    const int lane = tid & 63;
    const int wave = tid >> 6;            // 0..3
    const int l31  = lane & 31;
    const int hg   = lane >> 5;

    const int lin  = blockIdx.x;          // 0..511
    const int slot = lin >> 3;            // 0..63
    const int bh   = (lin & 7) + 8 * (slot >> 3);
    const int q0   = (slot & 7) * 256;

    const u16* Qh = Qhm + (size_t)bh * BHSTRIDE;
    const u16* Kh = Khm + (size_t)bh * BHSTRIDE;
    const u16* Vh = Vt  + (size_t)bh * BHSTRIDE;
    u16*       Oh = Ohm + (size_t)bh * BHSTRIDE;

    // ---- Q B-fragments straight from global (L2-resident, read once) ----
    // B-frag layout (32x32x16): lane holds col q = l31, k(d) = hg*8 + j.
    bf16x8 qbf[2][4];
#pragma unroll
    for (int qt = 0; qt < 2; ++qt)
#pragma unroll
        for (int dc = 0; dc < 4; ++dc)
            qbf[qt][dc] = *(const bf16x8*)(Qh +
                (size_t)(q0 + wave * 64 + qt * 32 + l31) * 64 + dc * 16 + hg * 8);

    f32x16 oaccA[2] = {};    // q-tile 0, [d-tile]
    f32x16 oaccB[2] = {};    // q-tile 1, [d-tile]
    float lsA[2] = {}, lsB[2] = {};   // 2-way split sums per q-tile

    const int krow8 = tid >> 3, kcp = tid & 7;     // K: 32 rows/it, 8 chunks
    const int vd16  = tid >> 4, vcp = tid & 15;    // Vt: 16 rows/it, 16 chunks

    auto stage = [&](int buf, int kt) {
#pragma unroll
        for (int it = 0; it < 4; ++it) {           // K tile: 128 keys x 64 d
            int row = it * 32 + krow8;
            int sc = kcp ^ (((row >> 3) ^ row) & 7);
            async_copy16(Kh + (size_t)(kt * 128 + row) * 64 + sc * 8,
                         (char*)(&sK[buf][0]) + it * 4096 + tid * 16);
        }
#pragma unroll
        for (int it = 0; it < 4; ++it) {           // Vt tile: 64 d x 128 keys
            int d = it * 16 + vd16;
            int sc = vcp ^ (d & 15);
            async_copy16(Vh + (size_t)d * 2048 + kt * 128 + sc * 8,
                         (char*)(&sVt[buf][0]) + it * 4096 + tid * 16);
        }
    };

    // QK^T for one 32-key chunk, BOTH q-tiles from one ka read.
    auto qk2 = [&](const u16* sKc, int kc, f32x16& sa0, f32x16& sa1) {
        sa0 = (f32x16){};
        sa1 = (f32x16){};
        const int krow = kc * 32 + l31;
        const int ksw = ((krow >> 3) ^ krow) & 7;
#pragma unroll
        for (int dc = 0; dc < 4; ++dc) {
            bf16x8 ka = *(const bf16x8*)(sKc + krow * 64 + ((dc * 2 + hg) ^ ksw) * 8);
            sa0 = MFMA32(ka, qbf[0][dc], sa0);
            sa1 = MFMA32(ka, qbf[1][dc], sa1);
        }
    };

    // softmax: exp2 + lsum + in-register bf16 A-frag build (cvt_pk+permlane)
    auto sm = [&](const f32x16& sa, bf16x8& o0, bf16x8& o1, float* ls) {
        float p[16];                         // p[r]=P[q=l31][crow(r,hg)]
#pragma unroll
        for (int r = 0; r < 16; ++r) p[r] = aexp2(sa[r]);
#pragma unroll
        for (int r = 0; r < 16; ++r) ls[r & 1] += p[r];
        uint32_t w0 = cvtpk(p[0],  p[1]),  w1 = cvtpk(p[2],  p[3]);
        uint32_t w2 = cvtpk(p[4],  p[5]),  w3 = cvtpk(p[6],  p[7]);
        uint32_t w4 = cvtpk(p[8],  p[9]),  w5 = cvtpk(p[10], p[11]);
        uint32_t w6 = cvtpk(p[12], p[13]), w7 = cvtpk(p[14], p[15]);
        plswap(w0, w2); plswap(w1, w3);     // keys 0-15 of chunk
        plswap(w4, w6); plswap(w5, w7);     // keys 16-31 of chunk
        o0 = mkfrag(w0, w1, w2, w3);
        o1 = mkfrag(w4, w5, w6, w7);
    };

    // PV for one 32-key chunk, BOTH q-tiles from one vb read.
    auto pv2 = [&](const u16* sVc, int kc, bf16x8 a0, bf16x8 a1,
                   bf16x8 b0, bf16x8 b1) {
        bf16x8 vb[2][2];
#pragma unroll
        for (int sub = 0; sub < 2; ++sub)
#pragma unroll
            for (int dt = 0; dt < 2; ++dt) {
                int dr = dt * 32 + l31;
                vb[sub][dt] = *(const bf16x8*)(sVc + dr * 128 +
                    ((kc * 4 + sub * 2 + hg) ^ (dr & 15)) * 8);
            }
        oaccA[0] = MFMA32(a0, vb[0][0], oaccA[0]);
        oaccA[1] = MFMA32(a0, vb[0][1], oaccA[1]);
        oaccB[0] = MFMA32(b0, vb[0][0], oaccB[0]);
        oaccB[1] = MFMA32(b0, vb[0][1], oaccB[1]);
        oaccA[0] = MFMA32(a1, vb[1][0], oaccA[0]);
        oaccA[1] = MFMA32(a1, vb[1][1], oaccA[1]);
        oaccB[0] = MFMA32(b1, vb[1][0], oaccB[0]);
        oaccB[1] = MFMA32(b1, vb[1][1], oaccB[1]);
    };

    stage(0, 0);
    __syncthreads();          // compiler drains vmcnt(0) before s_barrier

    int cur = 0;
    for (int kt = 0; kt < 16; ++kt) {
        const u16* sKc = &sK[cur][0];
        const u16* sVc = &sVt[cur][0];

        f32x16 sA, sB, nA, nB;
        qk2(sKc, 0, sA, sB);              // fill: chunk 0 for both q-tiles
        if (kt < 15) stage(cur ^ 1, kt + 1);
        FENCE();

        bf16x8 a0, a1, b0, b1;
        // kc = 0
        sm(sA, a0, a1, lsA);   FENCE();   // overlaps qk2(0) tail / stage
        qk2(sKc, 1, nA, nB);   FENCE();
        sm(sB, b0, b1, lsB);   FENCE();   // overlaps qk2(1)
        pv2(sVc, 0, a0, a1, b0, b1); FENCE();
        // kc = 1
        sm(nA, a0, a1, lsA);   FENCE();   // overlaps pv2(0)
        qk2(sKc, 2, sA, sB);   FENCE();
        sm(nB, b0, b1, lsB);   FENCE();   // overlaps qk2(2)
        pv2(sVc, 1, a0, a1, b0, b1); FENCE();
        // kc = 2
        sm(sA, a0, a1, lsA);   FENCE();
        qk2(sKc, 3, nA, nB);   FENCE();
        sm(sB, b0, b1, lsB);   FENCE();
        pv2(sVc, 2, a0, a1, b0, b1); FENCE();
        // kc = 3
        sm(nA, a0, a1, lsA);   FENCE();   // overlaps pv2(2)
        sm(nB, b0, b1, lsB);   FENCE();
        pv2(sVc, 3, a0, a1, b0, b1);

        __syncthreads();      // staged kt+1 visible; cur readers all done
        cur ^= 1;
    }

    // ---- epilogue: lane l31 holds lsum for q=l31 (half-sum); O rows are
    // crow(r,hg); redistribute 1/l via shfl, scalar bf16 stores ----
#pragma unroll
    for (int qt = 0; qt < 2; ++qt) {
        float l = qt ? (lsB[0] + lsB[1]) : (lsA[0] + lsA[1]);
        l += __shfl_xor(l, 32);
        float inv = 1.0f / l;
        const f32x16* oa = qt ? oaccB : oaccA;
#pragma unroll
        for (int r = 0; r < 16; ++r) {
            int row = (r & 3) + 4 * hg + 8 * (r >> 2);
            float invr = __shfl(inv, row);
            size_t grow = (size_t)q0 + wave * 64 + qt * 32 + row;
            Oh[grow * 64 + l31]      = f2bf(oa[0][r] * invr);
            Oh[grow * 64 + 32 + l31] = f2bf(oa[1][r] * invr);
        }
    }
}

// ---------------------------------------------------------------------------
extern "C" void kernel_launch(void* const* d_in, const int* in_sizes, int n_in,
                              void* d_out, int out_size, void* d_ws, size_t ws_size,
                              hipStream_t stream)
{
    const float* X    = (const float*)d_in[0];
    const float* R    = (const float*)d_in[1];
    const float* E    = (const float*)d_in[2];
    const float* Wq   = (const float*)d_in[3];
    const float* Wk   = (const float*)d_in[4];
    const float* Wv   = (const float*)d_in[5];
    const float* Wrot = (const float*)d_in[6];
    const float* Went = (const float*)d_in[7];
    const float* Wo   = (const float*)d_in[8];

    const size_t NT = 8192 * 1024;
    const size_t NW = 1024 * 1024;

    // d_out doubles as scratch for Qhm/Khm (bf16, head-major).
    u16* Qhm = (u16*)d_out;
    u16* Khm = Qhm + NT;
    // ws: Xb | Rb->Vt | Eb->Ohm | 6 bf16 weights
    u16* Xb  = (u16*)d_ws;
    u16* RVb = Xb + NT;    // rotation bf16, then V^T head-major
    u16* EOb = RVb + NT;   // entangle bf16, then O head-major
    u16* Wqb = EOb + NT;
    u16* Wkb   = Wqb + NW;
    u16* Wvb   = Wkb + NW;
    u16* Wrotb = Wvb + NW;
    u16* Wentb = Wrotb + NW;
    u16* Wob   = Wentb + NW;

    {   // activations
        CvtArgs a{};
        a.s[0] = X; a.s[1] = R; a.s[2] = E;
        a.d[0] = Xb; a.d[1] = RVb; a.d[2] = EOb;
        cvt_kernel<<<dim3(4096, 1, 3), 256, 0, stream>>>(a, (int)NT);
    }
    {   // weights
        CvtArgs a{};
        a.s[0] = Wq; a.s[1] = Wk; a.s[2] = Wv; a.s[3] = Wrot; a.s[4] = Went; a.s[5] = Wo;
        a.d[0] = Wqb; a.d[1] = Wkb; a.d[2] = Wvb; a.d[3] = Wrotb; a.d[4] = Wentb; a.d[5] = Wob;
        cvt_kernel<<<dim3(512, 1, 6), 256, 0, stream>>>(a, (int)NW);
    }

    dim3 gproj(64, 8);
    gemm_bt<0, 1><<<gproj, 256, 0, stream>>>(Xb, Wqb, RVb, Wrotb, Qhm, 1024, 2, GAMMA);
    gemm_bt<0, 1><<<gproj, 256, 0, stream>>>(Xb, Wkb, EOb, Wentb, Khm, 1024, 2, 1.0f);
    gemm_bt<0, 2><<<gproj, 256, 0, stream>>>(Xb, Wvb, nullptr, nullptr, RVb, 1024, 1, 1.0f);
    flash_kernel<<<dim3(512), 256, 0, stream>>>(Qhm, Khm, RVb, EOb);
    gemm_bt<1, 0><<<gproj, 256, 0, stream>>>(EOb, Wob, nullptr, nullptr, d_out, 1024, 1, 1.0f);
}

// Round 8
// 364.062 us; speedup vs baseline: 1.0157x; 1.0157x over previous
//
#include <hip/hip_runtime.h>
#include <stdint.h>

// B=4, S=2048, E=1024, H=16, D=64. fp32 I/O; bf16 MFMA compute.
// R11: GEMM round. Q-proj and K-proj fused into ONE launch (qk_proj):
// grid (64,16), by<8 -> Q (Xb*Wq + RVb*Wrot, GAMMA), by>=8 -> K
// (Xb*Wk + EOb*Went). 1024 blocks -> 3-4 blocks/CU (vs 512 -> 2): the
// m97-structure's barrier-drain stall now overlaps across resident
// blocks (m114 mechanism). Same-m blocks land on the same XCD (linear
// id mod 8 = x mod 8) -> Xb A-panel fetched once per XCD, reused 16x.
// launch_bounds (256,3) caps VGPR at 170 (no spill at current ~150).
// Flash identical to R10 (81.5 us, fenced 2-state x 64 q-rows/wave).

typedef unsigned short u16;
typedef __bf16 bf16x8 __attribute__((ext_vector_type(8)));
typedef float f32x4 __attribute__((ext_vector_type(4)));
typedef float f32x16 __attribute__((ext_vector_type(16)));
typedef uint32_t u32x4 __attribute__((ext_vector_type(4)));

#define MFMA_BF16(a, b, c) __builtin_amdgcn_mfma_f32_16x16x32_bf16((a), (b), (c), 0, 0, 0)
#define MFMA32(a, b, c)    __builtin_amdgcn_mfma_f32_32x32x16_bf16((a), (b), (c), 0, 0, 0)
#define GAMMA 0.18033688011112042f   // (1/8) * log2(e): folded into Q projection
#define BHSTRIDE 131072              // 2048 * 64 elems per (b,h) slice
#define FENCE() __builtin_amdgcn_sched_barrier(0)

static __device__ __forceinline__ u16 f2bf(float f) {
    uint32_t u = __builtin_bit_cast(uint32_t, f);
    u = (u + 0x7FFFu + ((u >> 16) & 1u)) >> 16;   // RNE
    return (u16)u;
}

static __device__ __forceinline__ uint32_t pk_rne2(float a, float b) {
    uint32_t ua = __builtin_bit_cast(uint32_t, a);
    uint32_t ub = __builtin_bit_cast(uint32_t, b);
    ua += 0x7FFFu + ((ua >> 16) & 1u);
    ub += 0x7FFFu + ((ub >> 16) & 1u);
    return __builtin_amdgcn_perm(ub, ua, 0x07060302);
}

static __device__ __forceinline__ void async_copy16(const void* g, void* l) {
    __builtin_amdgcn_global_load_lds((__attribute__((address_space(1))) void*)g,
                                     (__attribute__((address_space(3))) void*)l,
                                     16, 0, 0);
}

// raw hardware exp2: exactly one trans instruction, no libm range fixups
static __device__ __forceinline__ float aexp2(float x) {
    float r;
    asm("v_exp_f32 %0, %1" : "=v"(r) : "v"(x));
    return r;
}

// pack two f32 -> one u32 of 2 bf16 (lo=a, hi=b); no builtin on gfx950
static __device__ __forceinline__ uint32_t cvtpk(float a, float b) {
    uint32_t r;
    asm("v_cvt_pk_bf16_f32 %0, %1, %2" : "=v"(r) : "v"(a), "v"(b));
    return r;
}

// exchange a's upper 32 lanes with b's lower 32 lanes (both modified)
static __device__ __forceinline__ void plswap(uint32_t& a, uint32_t& b) {
    asm("v_permlane32_swap_b32 %0, %1" : "+v"(a), "+v"(b));
}

static __device__ __forceinline__ bf16x8 mkfrag(uint32_t w0, uint32_t w1,
                                                uint32_t w2, uint32_t w3) {
    u32x4 u = {w0, w1, w2, w3};
    return __builtin_bit_cast(bf16x8, u);
}

// ---------------------------------------------------------------------------
// fp32 -> bf16 batched converter.
// ---------------------------------------------------------------------------
struct CvtArgs { const float* s[6]; u16* d[6]; };

__global__ __launch_bounds__(256) void cvt_kernel(CvtArgs a, int nelem) {
    const float* s = a.s[blockIdx.z];
    u16* d = a.d[blockIdx.z];
    int i = (blockIdx.x * 256 + threadIdx.x) * 8;
    float4 f0 = *(const float4*)(s + i);
    float4 f1 = *(const float4*)(s + i + 4);
    uint4 w;
    w.x = pk_rne2(f0.x, f0.y); w.y = pk_rne2(f0.z, f0.w);
    w.z = pk_rne2(f1.x, f1.y); w.w = pk_rne2(f1.z, f1.w);
    *(uint4*)(d + i) = w;
}

// ---------------------------------------------------------------------------
// Fused Q/K projection: C = scale * (A0 @ W0^T + A1 @ W1^T), bf16,
// M=8192, N=K=1024 each, 128x128 tile, BK=64, head-major bf16 output.
// grid (64,16): blockIdx.y < 8 -> Q set, >= 8 -> K set (uniform select).
// Staging: linear LDS dest + pre-swizzled source + swizzled ds_read.
// ---------------------------------------------------------------------------
__global__ __launch_bounds__(256, 3) void qk_proj(
    const u16* __restrict__ Xb,
    const u16* __restrict__ Wqb, const u16* __restrict__ RVb,
    const u16* __restrict__ Wrotb, u16* __restrict__ Qhm,
    const u16* __restrict__ Wkb, const u16* __restrict__ EOb,
    const u16* __restrict__ Wentb, u16* __restrict__ Khm)
{
    __shared__ __align__(16) u16 lA[128 * 64];   // 16 KB
    __shared__ __align__(16) u16 lB[128 * 64];   // 16 KB

    const int tid  = threadIdx.x;
    const int lane = tid & 63;
    const int wave = tid >> 6;
    const int wm   = (wave >> 1) * 64;
    const int wn   = (wave & 1) * 64;
    const size_t m0 = (size_t)blockIdx.x * 128;

    const bool isK = blockIdx.y >= 8;
    const size_t n0 = (size_t)(blockIdx.y & 7) * 128;
    const u16* A0 = Xb;
    const u16* W0 = isK ? Wkb  : Wqb;
    const u16* A1 = isK ? EOb  : RVb;
    const u16* W1 = isK ? Wentb : Wrotb;
    u16*       C  = isK ? Khm  : Qhm;
    const float scale = isK ? 1.0f : GAMMA;

    const int row8 = tid >> 3;       // 0..31
    const int cp   = tid & 7;        // 16B chunk within 128B row
    const int fr   = lane & 15;
    const int g    = lane >> 4;      // 0..3

    f32x4 acc[4][4] = {};

    for (int p = 0; p < 2; ++p) {
        const u16* A = p ? A1 : A0;
        const u16* W = p ? W1 : W0;
        for (int k0 = 0; k0 < 1024; k0 += 64) {
            __syncthreads();
#pragma unroll
            for (int it = 0; it < 4; ++it) {
                int row = it * 32 + row8;
                int sc = cp ^ (((row >> 3) ^ row) & 7);
                async_copy16(A + ((m0 + row) * 1024 + k0 + sc * 8),
                             (char*)lA + it * 4096 + tid * 16);
                async_copy16(W + ((n0 + row) * 1024 + k0 + sc * 8),
                             (char*)lB + it * 4096 + tid * 16);
            }
            __syncthreads();

            bf16x8 af[4][2], bfm[4][2];
#pragma unroll
            for (int i = 0; i < 4; ++i) {
                int row = wm + i * 16 + fr;
                int sw = ((row >> 3) ^ row) & 7;
                af[i][0] = *(const bf16x8*)(lA + row * 64 + (g ^ sw) * 8);
                af[i][1] = *(const bf16x8*)(lA + row * 64 + ((4 + g) ^ sw) * 8);
            }
#pragma unroll
            for (int j = 0; j < 4; ++j) {
                int row = wn + j * 16 + fr;
                int sw = ((row >> 3) ^ row) & 7;
                bfm[j][0] = *(const bf16x8*)(lB + row * 64 + (g ^ sw) * 8);
                bfm[j][1] = *(const bf16x8*)(lB + row * 64 + ((4 + g) ^ sw) * 8);
            }
#pragma unroll
            for (int i = 0; i < 4; ++i)
#pragma unroll
                for (int j = 0; j < 4; ++j) {
                    acc[i][j] = MFMA_BF16(af[i][0], bfm[j][0], acc[i][j]);
                    acc[i][j] = MFMA_BF16(af[i][1], bfm[j][1], acc[i][j]);
                }
        }
    }

#pragma unroll
    for (int i = 0; i < 4; ++i)
#pragma unroll
        for (int j = 0; j < 4; ++j)
#pragma unroll
            for (int rg = 0; rg < 4; ++rg) {
                size_t row = m0 + wm + i * 16 + g * 4 + rg;
                size_t col = n0 + wn + j * 16 + fr;
                size_t addr = ((row >> 11) * 16 + (col >> 6)) * BHSTRIDE
                            + (row & 2047) * 64 + (col & 63);
                C[addr] = f2bf(acc[i][j][rg] * scale);
            }
}

// ---------------------------------------------------------------------------
// C = scale * sum_p A_p @ W_p^T, bf16, M=8192, N=K=1024, 128x128 tile, BK=64.
// (R6 version; used for V-proj and O-proj.)
// AMODE: 0 = A natural row-major (M x K); 1 = A head-major [bh][s][64].
// CMODE: 0 = fp32 natural; 2 = bf16 transposed head-major [bh][d][s].
// ---------------------------------------------------------------------------
template <int AMODE, int CMODE>
__global__ __launch_bounds__(256, 2) void gemm_bt(
    const u16* __restrict__ A0, const u16* __restrict__ W0,
    const u16* __restrict__ A1, const u16* __restrict__ W1,
    void* __restrict__ Cv, int K, int npairs, float scale)
{
    __shared__ __align__(16) u16 lA[128 * 64];   // 16 KB
    __shared__ __align__(16) u16 lB[128 * 64];   // 16 KB

    const int tid  = threadIdx.x;
    const int lane = tid & 63;
    const int wave = tid >> 6;
    const int wm   = (wave >> 1) * 64;
    const int wn   = (wave & 1) * 64;
    const size_t m0 = (size_t)blockIdx.x * 128;
    const size_t n0 = (size_t)blockIdx.y * 128;

    const int row8 = tid >> 3;       // 0..31
    const int cp   = tid & 7;        // 16B chunk within 128B row
    const int fr   = lane & 15;
    const int g    = lane >> 4;      // 0..3

    const size_t bb = (m0 >> 11) * 16;   // b*16 (tile never straddles a batch)
    const size_t s0 = m0 & 2047;

    f32x4 acc[4][4] = {};

    for (int p = 0; p < npairs; ++p) {
        const u16* A = p ? A1 : A0;
        const u16* W = p ? W1 : W0;
        for (int k0 = 0; k0 < K; k0 += 64) {
            __syncthreads();
#pragma unroll
            for (int it = 0; it < 4; ++it) {
                int row = it * 32 + row8;
                int sc = cp ^ (((row >> 3) ^ row) & 7);
                if (AMODE == 0) {
                    async_copy16(A + ((m0 + row) * (size_t)K + k0 + sc * 8),
                                 (char*)lA + it * 4096 + tid * 16);
                } else {
                    // head-major: k-step of 64 == exactly one head's D slice
                    size_t base = (bb + (size_t)(k0 >> 6)) * BHSTRIDE;
                    async_copy16(A + base + (s0 + row) * 64 + sc * 8,
                                 (char*)lA + it * 4096 + tid * 16);
                }
                async_copy16(W + ((n0 + row) * (size_t)K + k0 + sc * 8),
                             (char*)lB + it * 4096 + tid * 16);
            }
            __syncthreads();

            bf16x8 af[4][2], bfm[4][2];
#pragma unroll
            for (int i = 0; i < 4; ++i) {
                int row = wm + i * 16 + fr;
                int sw = ((row >> 3) ^ row) & 7;
                af[i][0] = *(const bf16x8*)(lA + row * 64 + (g ^ sw) * 8);
                af[i][1] = *(const bf16x8*)(lA + row * 64 + ((4 + g) ^ sw) * 8);
            }
#pragma unroll
            for (int j = 0; j < 4; ++j) {
                int row = wn + j * 16 + fr;
                int sw = ((row >> 3) ^ row) & 7;
                bfm[j][0] = *(const bf16x8*)(lB + row * 64 + (g ^ sw) * 8);
                bfm[j][1] = *(const bf16x8*)(lB + row * 64 + ((4 + g) ^ sw) * 8);
            }
#pragma unroll
            for (int i = 0; i < 4; ++i)
#pragma unroll
                for (int j = 0; j < 4; ++j) {
                    acc[i][j] = MFMA_BF16(af[i][0], bfm[j][0], acc[i][j]);
                    acc[i][j] = MFMA_BF16(af[i][1], bfm[j][1], acc[i][j]);
                }
        }
    }

#pragma unroll
    for (int i = 0; i < 4; ++i)
#pragma unroll
        for (int j = 0; j < 4; ++j) {
            if (CMODE == 2) {
                size_t row0 = m0 + wm + i * 16 + g * 4;        // 4 consecutive tokens
                size_t col  = n0 + wn + j * 16 + fr;
                size_t addr = ((row0 >> 11) * 16 + (col >> 6)) * BHSTRIDE
                            + (size_t)(col & 63) * 2048 + (row0 & 2047);
                ushort4 pk;
                pk.x = f2bf(acc[i][j][0] * scale);
                pk.y = f2bf(acc[i][j][1] * scale);
                pk.z = f2bf(acc[i][j][2] * scale);
                pk.w = f2bf(acc[i][j][3] * scale);
                *(ushort4*)((u16*)Cv + addr) = pk;
            } else {
#pragma unroll
                for (int rg = 0; rg < 4; ++rg) {
                    size_t row = m0 + wm + i * 16 + g * 4 + rg;
                    size_t col = n0 + wn + j * 16 + fr;
                    float v = acc[i][j][rg] * scale;
                    if (CMODE == 0) {
                        ((float*)Cv)[row * 1024 + col] = v;
                    } else {
                        size_t addr = ((row >> 11) * 16 + (col >> 6)) * BHSTRIDE
                                    + (row & 2047) * 64 + (col & 63);
                        ((u16*)Cv)[addr] = f2bf(v);
                    }
                }
            }
        }
}

// ---------------------------------------------------------------------------
// Flash attention (identical to R10): 32x32x16 MFMA, swapped QK^T,
// in-register P, fenced 2-state pipeline over TWO q-tiles per wave.
// ---------------------------------------------------------------------------
__global__ __launch_bounds__(256, 2) void flash_kernel(
    const u16* __restrict__ Qhm, const u16* __restrict__ Khm,
    const u16* __restrict__ Vt, u16* __restrict__ Ohm)
{
    __shared__ __align__(16) u16 sK[2][128 * 64];    // 32 KB
    __shared__ __align__(16) u16 sVt[2][64 * 128];   // 32 KB

    const int tid  = threadIdx.x;
    const int lane = tid & 63;
    const int wave = tid >> 6;            // 0..3
    const int l31  = lane & 31;
    const int hg   = lane >> 5;

    const int lin  = blockIdx.x;          // 0..511
    const int slot = lin >> 3;            // 0..63
    const int bh   = (lin & 7) + 8 * (slot >> 3);
    const int q0   = (slot & 7) * 256;

    const u16* Qh = Qhm + (size_t)bh * BHSTRIDE;
    const u16* Kh = Khm + (size_t)bh * BHSTRIDE;
    const u16* Vh = Vt  + (size_t)bh * BHSTRIDE;
    u16*       Oh = Ohm + (size_t)bh * BHSTRIDE;

    bf16x8 qbf[2][4];
#pragma unroll
    for (int qt = 0; qt < 2; ++qt)
#pragma unroll
        for (int dc = 0; dc < 4; ++dc)
            qbf[qt][dc] = *(const bf16x8*)(Qh +
                (size_t)(q0 + wave * 64 + qt * 32 + l31) * 64 + dc * 16 + hg * 8);

    f32x16 oaccA[2] = {};    // q-tile 0, [d-tile]
    f32x16 oaccB[2] = {};    // q-tile 1, [d-tile]
    float lsA[2] = {}, lsB[2] = {};   // 2-way split sums per q-tile

    const int krow8 = tid >> 3, kcp = tid & 7;     // K: 32 rows/it, 8 chunks
    const int vd16  = tid >> 4, vcp = tid & 15;    // Vt: 16 rows/it, 16 chunks

    auto stage = [&](int buf, int kt) {
#pragma unroll
        for (int it = 0; it < 4; ++it) {           // K tile: 128 keys x 64 d
            int row = it * 32 + krow8;
            int sc = kcp ^ (((row >> 3) ^ row) & 7);
            async_copy16(Kh + (size_t)(kt * 128 + row) * 64 + sc * 8,
                         (char*)(&sK[buf][0]) + it * 4096 + tid * 16);
        }
#pragma unroll
        for (int it = 0; it < 4; ++it) {           // Vt tile: 64 d x 128 keys
            int d = it * 16 + vd16;
            int sc = vcp ^ (d & 15);
            async_copy16(Vh + (size_t)d * 2048 + kt * 128 + sc * 8,
                         (char*)(&sVt[buf][0]) + it * 4096 + tid * 16);
        }
    };

    auto qk2 = [&](const u16* sKc, int kc, f32x16& sa0, f32x16& sa1) {
        sa0 = (f32x16){};
        sa1 = (f32x16){};
        const int krow = kc * 32 + l31;
        const int ksw = ((krow >> 3) ^ krow) & 7;
#pragma unroll
        for (int dc = 0; dc < 4; ++dc) {
            bf16x8 ka = *(const bf16x8*)(sKc + krow * 64 + ((dc * 2 + hg) ^ ksw) * 8);
            sa0 = MFMA32(ka, qbf[0][dc], sa0);
            sa1 = MFMA32(ka, qbf[1][dc], sa1);
        }
    };

    auto sm = [&](const f32x16& sa, bf16x8& o0, bf16x8& o1, float* ls) {
        float p[16];                         // p[r]=P[q=l31][crow(r,hg)]
#pragma unroll
        for (int r = 0; r < 16; ++r) p[r] = aexp2(sa[r]);
#pragma unroll
        for (int r = 0; r < 16; ++r) ls[r & 1] += p[r];
        uint32_t w0 = cvtpk(p[0],  p[1]),  w1 = cvtpk(p[2],  p[3]);
        uint32_t w2 = cvtpk(p[4],  p[5]),  w3 = cvtpk(p[6],  p[7]);
        uint32_t w4 = cvtpk(p[8],  p[9]),  w5 = cvtpk(p[10], p[11]);
        uint32_t w6 = cvtpk(p[12], p[13]), w7 = cvtpk(p[14], p[15]);
        plswap(w0, w2); plswap(w1, w3);     // keys 0-15 of chunk
        plswap(w4, w6); plswap(w5, w7);     // keys 16-31 of chunk
        o0 = mkfrag(w0, w1, w2, w3);
        o1 = mkfrag(w4, w5, w6, w7);
    };

    auto pv2 = [&](const u16* sVc, int kc, bf16x8 a0, bf16x8 a1,
                   bf16x8 b0, bf16x8 b1) {
        bf16x8 vb[2][2];
#pragma unroll
        for (int sub = 0; sub < 2; ++sub)
#pragma unroll
            for (int dt = 0; dt < 2; ++dt) {
                int dr = dt * 32 + l31;
                vb[sub][dt] = *(const bf16x8*)(sVc + dr * 128 +
                    ((kc * 4 + sub * 2 + hg) ^ (dr & 15)) * 8);
            }
        oaccA[0] = MFMA32(a0, vb[0][0], oaccA[0]);
        oaccA[1] = MFMA32(a0, vb[0][1], oaccA[1]);
        oaccB[0] = MFMA32(b0, vb[0][0], oaccB[0]);
        oaccB[1] = MFMA32(b0, vb[0][1], oaccB[1]);
        oaccA[0] = MFMA32(a1, vb[1][0], oaccA[0]);
        oaccA[1] = MFMA32(a1, vb[1][1], oaccA[1]);
        oaccB[0] = MFMA32(b1, vb[1][0], oaccB[0]);
        oaccB[1] = MFMA32(b1, vb[1][1], oaccB[1]);
    };

    stage(0, 0);
    __syncthreads();          // compiler drains vmcnt(0) before s_barrier

    int cur = 0;
    for (int kt = 0; kt < 16; ++kt) {
        const u16* sKc = &sK[cur][0];
        const u16* sVc = &sVt[cur][0];

        f32x16 sA, sB, nA, nB;
        qk2(sKc, 0, sA, sB);              // fill: chunk 0 for both q-tiles
        if (kt < 15) stage(cur ^ 1, kt + 1);
        FENCE();

        bf16x8 a0, a1, b0, b1;
        // kc = 0
        sm(sA, a0, a1, lsA);   FENCE();
        qk2(sKc, 1, nA, nB);   FENCE();
        sm(sB, b0, b1, lsB);   FENCE();
        pv2(sVc, 0, a0, a1, b0, b1); FENCE();
        // kc = 1
        sm(nA, a0, a1, lsA);   FENCE();
        qk2(sKc, 2, sA, sB);   FENCE();
        sm(nB, b0, b1, lsB);   FENCE();
        pv2(sVc, 1, a0, a1, b0, b1); FENCE();
        // kc = 2
        sm(sA, a0, a1, lsA);   FENCE();
        qk2(sKc, 3, nA, nB);   FENCE();
        sm(sB, b0, b1, lsB);   FENCE();
        pv2(sVc, 2, a0, a1, b0, b1); FENCE();
        // kc = 3
        sm(nA, a0, a1, lsA);   FENCE();
        sm(nB, b0, b1, lsB);   FENCE();
        pv2(sVc, 3, a0, a1, b0, b1);

        __syncthreads();      // staged kt+1 visible; cur readers all done
        cur ^= 1;
    }

    // ---- epilogue ----
#pragma unroll
    for (int qt = 0; qt < 2; ++qt) {
        float l = qt ? (lsB[0] + lsB[1]) : (lsA[0] + lsA[1]);
        l += __shfl_xor(l, 32);
        float inv = 1.0f / l;
        const f32x16* oa = qt ? oaccB : oaccA;
#pragma unroll
        for (int r = 0; r < 16; ++r) {
            int row = (r & 3) + 4 * hg + 8 * (r >> 2);
            float invr = __shfl(inv, row);
            size_t grow = (size_t)q0 + wave * 64 + qt * 32 + row;
            Oh[grow * 64 + l31]      = f2bf(oa[0][r] * invr);
            Oh[grow * 64 + 32 + l31] = f2bf(oa[1][r] * invr);
        }
    }
}

// ---------------------------------------------------------------------------
extern "C" void kernel_launch(void* const* d_in, const int* in_sizes, int n_in,
                              void* d_out, int out_size, void* d_ws, size_t ws_size,
                              hipStream_t stream)
{
    const float* X    = (const float*)d_in[0];
    const float* R    = (const float*)d_in[1];
    const float* E    = (const float*)d_in[2];
    const float* Wq   = (const float*)d_in[3];
    const float* Wk   = (const float*)d_in[4];
    const float* Wv   = (const float*)d_in[5];
    const float* Wrot = (const float*)d_in[6];
    const float* Went = (const float*)d_in[7];
    const float* Wo   = (const float*)d_in[8];

    const size_t NT = 8192 * 1024;
    const size_t NW = 1024 * 1024;

    // d_out doubles as scratch for Qhm/Khm (bf16, head-major).
    u16* Qhm = (u16*)d_out;
    u16* Khm = Qhm + NT;
    // ws: Xb | Rb->Vt | Eb->Ohm | 6 bf16 weights
    u16* Xb  = (u16*)d_ws;
    u16* RVb = Xb + NT;    // rotation bf16, then V^T head-major
    u16* EOb = RVb + NT;   // entangle bf16, then O head-major
    u16* Wqb = EOb + NT;
    u16* Wkb   = Wqb + NW;
    u16* Wvb   = Wkb + NW;
    u16* Wrotb = Wvb + NW;
    u16* Wentb = Wrotb + NW;
    u16* Wob   = Wentb + NW;

    {   // activations
        CvtArgs a{};
        a.s[0] = X; a.s[1] = R; a.s[2] = E;
        a.d[0] = Xb; a.d[1] = RVb; a.d[2] = EOb;
        cvt_kernel<<<dim3(4096, 1, 3), 256, 0, stream>>>(a, (int)NT);
    }
    {   // weights
        CvtArgs a{};
        a.s[0] = Wq; a.s[1] = Wk; a.s[2] = Wv; a.s[3] = Wrot; a.s[4] = Went; a.s[5] = Wo;
        a.d[0] = Wqb; a.d[1] = Wkb; a.d[2] = Wvb; a.d[3] = Wrotb; a.d[4] = Wentb; a.d[5] = Wob;
        cvt_kernel<<<dim3(512, 1, 6), 256, 0, stream>>>(a, (int)NW);
    }

    // Fused Q+K projections: 1024 blocks -> 3-4 blocks/CU.
    qk_proj<<<dim3(64, 16), 256, 0, stream>>>(Xb, Wqb, RVb, Wrotb, Qhm,
                                              Wkb, EOb, Wentb, Khm);
    // V projection (overwrites RVb with Vt AFTER qk_proj consumed rotation).
    gemm_bt<0, 2><<<dim3(64, 8), 256, 0, stream>>>(Xb, Wvb, nullptr, nullptr,
                                                   RVb, 1024, 1, 1.0f);
    flash_kernel<<<dim3(512), 256, 0, stream>>>(Qhm, Khm, RVb, EOb);
    gemm_bt<1, 0><<<dim3(64, 8), 256, 0, stream>>>(EOb, Wob, nullptr, nullptr,
                                                   d_out, 1024, 1, 1.0f);
}

// Round 9
// 336.820 us; speedup vs baseline: 1.0978x; 1.0809x over previous
//
#include <hip/hip_runtime.h>
#include <stdint.h>

// B=4, S=2048, E=1024, H=16, D=64. fp32 I/O; bf16 MFMA compute.
// R12: launch-count + overlap round.
//  - cvt: ONE launch (z=0..8; weight slices early-exit x>=512).
//  - qkv_proj: Q/K/V projections fused in one launch, grid (64,24):
//    y<8 Q, y<16 K, else V. V writes Vt into a NEW ws region (after the
//    weights) -- requires ws_size >= 4*NT+6*NW elems; else falls back to
//    R11's qk_proj + separate V-proj (Vt into RVb). Runtime host check.
//    6 blocks/CU pool (LDS-capped 5): Q/K stragglers overlap V blocks.
//  - flash (81.5 us) and O-proj unchanged.

typedef unsigned short u16;
typedef __bf16 bf16x8 __attribute__((ext_vector_type(8)));
typedef float f32x4 __attribute__((ext_vector_type(4)));
typedef float f32x16 __attribute__((ext_vector_type(16)));
typedef uint32_t u32x4 __attribute__((ext_vector_type(4)));

#define MFMA_BF16(a, b, c) __builtin_amdgcn_mfma_f32_16x16x32_bf16((a), (b), (c), 0, 0, 0)
#define MFMA32(a, b, c)    __builtin_amdgcn_mfma_f32_32x32x16_bf16((a), (b), (c), 0, 0, 0)
#define GAMMA 0.18033688011112042f   // (1/8) * log2(e): folded into Q projection
#define BHSTRIDE 131072              // 2048 * 64 elems per (b,h) slice
#define FENCE() __builtin_amdgcn_sched_barrier(0)

static __device__ __forceinline__ u16 f2bf(float f) {
    uint32_t u = __builtin_bit_cast(uint32_t, f);
    u = (u + 0x7FFFu + ((u >> 16) & 1u)) >> 16;   // RNE
    return (u16)u;
}

static __device__ __forceinline__ uint32_t pk_rne2(float a, float b) {
    uint32_t ua = __builtin_bit_cast(uint32_t, a);
    uint32_t ub = __builtin_bit_cast(uint32_t, b);
    ua += 0x7FFFu + ((ua >> 16) & 1u);
    ub += 0x7FFFu + ((ub >> 16) & 1u);
    return __builtin_amdgcn_perm(ub, ua, 0x07060302);
}

static __device__ __forceinline__ void async_copy16(const void* g, void* l) {
    __builtin_amdgcn_global_load_lds((__attribute__((address_space(1))) void*)g,
                                     (__attribute__((address_space(3))) void*)l,
                                     16, 0, 0);
}

// raw hardware exp2: exactly one trans instruction, no libm range fixups
static __device__ __forceinline__ float aexp2(float x) {
    float r;
    asm("v_exp_f32 %0, %1" : "=v"(r) : "v"(x));
    return r;
}

// pack two f32 -> one u32 of 2 bf16 (lo=a, hi=b); no builtin on gfx950
static __device__ __forceinline__ uint32_t cvtpk(float a, float b) {
    uint32_t r;
    asm("v_cvt_pk_bf16_f32 %0, %1, %2" : "=v"(r) : "v"(a), "v"(b));
    return r;
}

// exchange a's upper 32 lanes with b's lower 32 lanes (both modified)
static __device__ __forceinline__ void plswap(uint32_t& a, uint32_t& b) {
    asm("v_permlane32_swap_b32 %0, %1" : "+v"(a), "+v"(b));
}

static __device__ __forceinline__ bf16x8 mkfrag(uint32_t w0, uint32_t w1,
                                                uint32_t w2, uint32_t w3) {
    u32x4 u = {w0, w1, w2, w3};
    return __builtin_bit_cast(bf16x8, u);
}

// ---------------------------------------------------------------------------
// fp32 -> bf16 batched converter. z<3: activations (8M elems, 4096 blocks);
// z>=3: weights (1M elems, blocks x>=512 exit).
// ---------------------------------------------------------------------------
struct CvtArgs { const float* s[9]; u16* d[9]; };

__global__ __launch_bounds__(256) void cvt_kernel(CvtArgs a) {
    if (blockIdx.z >= 3 && blockIdx.x >= 512) return;
    const float* s = a.s[blockIdx.z];
    u16* d = a.d[blockIdx.z];
    int i = (blockIdx.x * 256 + threadIdx.x) * 8;
    float4 f0 = *(const float4*)(s + i);
    float4 f1 = *(const float4*)(s + i + 4);
    uint4 w;
    w.x = pk_rne2(f0.x, f0.y); w.y = pk_rne2(f0.z, f0.w);
    w.z = pk_rne2(f1.x, f1.y); w.w = pk_rne2(f1.z, f1.w);
    *(uint4*)(d + i) = w;
}

// ---------------------------------------------------------------------------
// Fused Q/K/V projection. grid (64, 24): y<8 -> Q (Xb*Wq + RVb*Wrot, GAMMA,
// head-major out Qhm); y<16 -> K (Xb*Wk + EOb*Went, Khm); y>=16 -> V
// (Xb*Wv, transposed head-major out Vt). 128x128 tile, BK=64.
// Staging: linear LDS dest + pre-swizzled source + swizzled ds_read.
// ---------------------------------------------------------------------------
__global__ __launch_bounds__(256, 3) void qkv_proj(
    const u16* __restrict__ Xb,
    const u16* __restrict__ Wqb, const u16* __restrict__ RVb,
    const u16* __restrict__ Wrotb, u16* __restrict__ Qhm,
    const u16* __restrict__ Wkb, const u16* __restrict__ EOb,
    const u16* __restrict__ Wentb, u16* __restrict__ Khm,
    const u16* __restrict__ Wvb, u16* __restrict__ Vt)
{
    __shared__ __align__(16) u16 lA[128 * 64];   // 16 KB
    __shared__ __align__(16) u16 lB[128 * 64];   // 16 KB

    const int tid  = threadIdx.x;
    const int lane = tid & 63;
    const int wave = tid >> 6;
    const int wm   = (wave >> 1) * 64;
    const int wn   = (wave & 1) * 64;
    const size_t m0 = (size_t)blockIdx.x * 128;

    const int sel = blockIdx.y >> 3;          // 0=Q 1=K 2=V
    const size_t n0 = (size_t)(blockIdx.y & 7) * 128;
    const u16* W0 = sel == 0 ? Wqb : (sel == 1 ? Wkb : Wvb);
    const u16* A1 = sel == 1 ? EOb : RVb;
    const u16* W1 = sel == 1 ? Wentb : Wrotb;
    const float scale = sel == 0 ? GAMMA : 1.0f;
    const int npairs = sel == 2 ? 1 : 2;

    const int row8 = tid >> 3;       // 0..31
    const int cp   = tid & 7;        // 16B chunk within 128B row
    const int fr   = lane & 15;
    const int g    = lane >> 4;      // 0..3

    f32x4 acc[4][4] = {};

    for (int p = 0; p < npairs; ++p) {
        const u16* A = p ? A1 : Xb;
        const u16* W = p ? W1 : W0;
        for (int k0 = 0; k0 < 1024; k0 += 64) {
            __syncthreads();
#pragma unroll
            for (int it = 0; it < 4; ++it) {
                int row = it * 32 + row8;
                int sc = cp ^ (((row >> 3) ^ row) & 7);
                async_copy16(A + ((m0 + row) * 1024 + k0 + sc * 8),
                             (char*)lA + it * 4096 + tid * 16);
                async_copy16(W + ((n0 + row) * 1024 + k0 + sc * 8),
                             (char*)lB + it * 4096 + tid * 16);
            }
            __syncthreads();

            bf16x8 af[4][2], bfm[4][2];
#pragma unroll
            for (int i = 0; i < 4; ++i) {
                int row = wm + i * 16 + fr;
                int sw = ((row >> 3) ^ row) & 7;
                af[i][0] = *(const bf16x8*)(lA + row * 64 + (g ^ sw) * 8);
                af[i][1] = *(const bf16x8*)(lA + row * 64 + ((4 + g) ^ sw) * 8);
            }
#pragma unroll
            for (int j = 0; j < 4; ++j) {
                int row = wn + j * 16 + fr;
                int sw = ((row >> 3) ^ row) & 7;
                bfm[j][0] = *(const bf16x8*)(lB + row * 64 + (g ^ sw) * 8);
                bfm[j][1] = *(const bf16x8*)(lB + row * 64 + ((4 + g) ^ sw) * 8);
            }
#pragma unroll
            for (int i = 0; i < 4; ++i)
#pragma unroll
                for (int j = 0; j < 4; ++j) {
                    acc[i][j] = MFMA_BF16(af[i][0], bfm[j][0], acc[i][j]);
                    acc[i][j] = MFMA_BF16(af[i][1], bfm[j][1], acc[i][j]);
                }
        }
    }

    if (sel == 2) {
        // V: transposed head-major [bh][d][s], packed 4-token stores
#pragma unroll
        for (int i = 0; i < 4; ++i)
#pragma unroll
            for (int j = 0; j < 4; ++j) {
                size_t row0 = m0 + wm + i * 16 + g * 4;
                size_t col  = n0 + wn + j * 16 + fr;
                size_t addr = ((row0 >> 11) * 16 + (col >> 6)) * BHSTRIDE
                            + (size_t)(col & 63) * 2048 + (row0 & 2047);
                ushort4 pk;
                pk.x = f2bf(acc[i][j][0]);
                pk.y = f2bf(acc[i][j][1]);
                pk.z = f2bf(acc[i][j][2]);
                pk.w = f2bf(acc[i][j][3]);
                *(ushort4*)(Vt + addr) = pk;
            }
    } else {
        u16* C = sel == 0 ? Qhm : Khm;
#pragma unroll
        for (int i = 0; i < 4; ++i)
#pragma unroll
            for (int j = 0; j < 4; ++j)
#pragma unroll
                for (int rg = 0; rg < 4; ++rg) {
                    size_t row = m0 + wm + i * 16 + g * 4 + rg;
                    size_t col = n0 + wn + j * 16 + fr;
                    size_t addr = ((row >> 11) * 16 + (col >> 6)) * BHSTRIDE
                                + (row & 2047) * 64 + (col & 63);
                    C[addr] = f2bf(acc[i][j][rg] * scale);
                }
    }
}

// ---------------------------------------------------------------------------
// Fused Q/K projection (fallback when ws too small for a separate Vt).
// ---------------------------------------------------------------------------
__global__ __launch_bounds__(256, 3) void qk_proj(
    const u16* __restrict__ Xb,
    const u16* __restrict__ Wqb, const u16* __restrict__ RVb,
    const u16* __restrict__ Wrotb, u16* __restrict__ Qhm,
    const u16* __restrict__ Wkb, const u16* __restrict__ EOb,
    const u16* __restrict__ Wentb, u16* __restrict__ Khm)
{
    __shared__ __align__(16) u16 lA[128 * 64];   // 16 KB
    __shared__ __align__(16) u16 lB[128 * 64];   // 16 KB

    const int tid  = threadIdx.x;
    const int lane = tid & 63;
    const int wave = tid >> 6;
    const int wm   = (wave >> 1) * 64;
    const int wn   = (wave & 1) * 64;
    const size_t m0 = (size_t)blockIdx.x * 128;

    const bool isK = blockIdx.y >= 8;
    const size_t n0 = (size_t)(blockIdx.y & 7) * 128;
    const u16* W0 = isK ? Wkb  : Wqb;
    const u16* A1 = isK ? EOb  : RVb;
    const u16* W1 = isK ? Wentb : Wrotb;
    u16*       C  = isK ? Khm  : Qhm;
    const float scale = isK ? 1.0f : GAMMA;

    const int row8 = tid >> 3;
    const int cp   = tid & 7;
    const int fr   = lane & 15;
    const int g    = lane >> 4;

    f32x4 acc[4][4] = {};

    for (int p = 0; p < 2; ++p) {
        const u16* A = p ? A1 : Xb;
        const u16* W = p ? W1 : W0;
        for (int k0 = 0; k0 < 1024; k0 += 64) {
            __syncthreads();
#pragma unroll
            for (int it = 0; it < 4; ++it) {
                int row = it * 32 + row8;
                int sc = cp ^ (((row >> 3) ^ row) & 7);
                async_copy16(A + ((m0 + row) * 1024 + k0 + sc * 8),
                             (char*)lA + it * 4096 + tid * 16);
                async_copy16(W + ((n0 + row) * 1024 + k0 + sc * 8),
                             (char*)lB + it * 4096 + tid * 16);
            }
            __syncthreads();

            bf16x8 af[4][2], bfm[4][2];
#pragma unroll
            for (int i = 0; i < 4; ++i) {
                int row = wm + i * 16 + fr;
                int sw = ((row >> 3) ^ row) & 7;
                af[i][0] = *(const bf16x8*)(lA + row * 64 + (g ^ sw) * 8);
                af[i][1] = *(const bf16x8*)(lA + row * 64 + ((4 + g) ^ sw) * 8);
            }
#pragma unroll
            for (int j = 0; j < 4; ++j) {
                int row = wn + j * 16 + fr;
                int sw = ((row >> 3) ^ row) & 7;
                bfm[j][0] = *(const bf16x8*)(lB + row * 64 + (g ^ sw) * 8);
                bfm[j][1] = *(const bf16x8*)(lB + row * 64 + ((4 + g) ^ sw) * 8);
            }
#pragma unroll
            for (int i = 0; i < 4; ++i)
#pragma unroll
                for (int j = 0; j < 4; ++j) {
                    acc[i][j] = MFMA_BF16(af[i][0], bfm[j][0], acc[i][j]);
                    acc[i][j] = MFMA_BF16(af[i][1], bfm[j][1], acc[i][j]);
                }
        }
    }

#pragma unroll
    for (int i = 0; i < 4; ++i)
#pragma unroll
        for (int j = 0; j < 4; ++j)
#pragma unroll
            for (int rg = 0; rg < 4; ++rg) {
                size_t row = m0 + wm + i * 16 + g * 4 + rg;
                size_t col = n0 + wn + j * 16 + fr;
                size_t addr = ((row >> 11) * 16 + (col >> 6)) * BHSTRIDE
                            + (row & 2047) * 64 + (col & 63);
                C[addr] = f2bf(acc[i][j][rg] * scale);
            }
}

// ---------------------------------------------------------------------------
// C = scale * sum_p A_p @ W_p^T (R6 version; V-proj fallback and O-proj).
// ---------------------------------------------------------------------------
template <int AMODE, int CMODE>
__global__ __launch_bounds__(256, 2) void gemm_bt(
    const u16* __restrict__ A0, const u16* __restrict__ W0,
    const u16* __restrict__ A1, const u16* __restrict__ W1,
    void* __restrict__ Cv, int K, int npairs, float scale)
{
    __shared__ __align__(16) u16 lA[128 * 64];
    __shared__ __align__(16) u16 lB[128 * 64];

    const int tid  = threadIdx.x;
    const int lane = tid & 63;
    const int wave = tid >> 6;
    const int wm   = (wave >> 1) * 64;
    const int wn   = (wave & 1) * 64;
    const size_t m0 = (size_t)blockIdx.x * 128;
    const size_t n0 = (size_t)blockIdx.y * 128;

    const int row8 = tid >> 3;
    const int cp   = tid & 7;
    const int fr   = lane & 15;
    const int g    = lane >> 4;

    const size_t bb = (m0 >> 11) * 16;
    const size_t s0 = m0 & 2047;

    f32x4 acc[4][4] = {};

    for (int p = 0; p < npairs; ++p) {
        const u16* A = p ? A1 : A0;
        const u16* W = p ? W1 : W0;
        for (int k0 = 0; k0 < K; k0 += 64) {
            __syncthreads();
#pragma unroll
            for (int it = 0; it < 4; ++it) {
                int row = it * 32 + row8;
                int sc = cp ^ (((row >> 3) ^ row) & 7);
                if (AMODE == 0) {
                    async_copy16(A + ((m0 + row) * (size_t)K + k0 + sc * 8),
                                 (char*)lA + it * 4096 + tid * 16);
                } else {
                    size_t base = (bb + (size_t)(k0 >> 6)) * BHSTRIDE;
                    async_copy16(A + base + (s0 + row) * 64 + sc * 8,
                                 (char*)lA + it * 4096 + tid * 16);
                }
                async_copy16(W + ((n0 + row) * (size_t)K + k0 + sc * 8),
                             (char*)lB + it * 4096 + tid * 16);
            }
            __syncthreads();

            bf16x8 af[4][2], bfm[4][2];
#pragma unroll
            for (int i = 0; i < 4; ++i) {
                int row = wm + i * 16 + fr;
                int sw = ((row >> 3) ^ row) & 7;
                af[i][0] = *(const bf16x8*)(lA + row * 64 + (g ^ sw) * 8);
                af[i][1] = *(const bf16x8*)(lA + row * 64 + ((4 + g) ^ sw) * 8);
            }
#pragma unroll
            for (int j = 0; j < 4; ++j) {
                int row = wn + j * 16 + fr;
                int sw = ((row >> 3) ^ row) & 7;
                bfm[j][0] = *(const bf16x8*)(lB + row * 64 + (g ^ sw) * 8);
                bfm[j][1] = *(const bf16x8*)(lB + row * 64 + ((4 + g) ^ sw) * 8);
            }
#pragma unroll
            for (int i = 0; i < 4; ++i)
#pragma unroll
                for (int j = 0; j < 4; ++j) {
                    acc[i][j] = MFMA_BF16(af[i][0], bfm[j][0], acc[i][j]);
                    acc[i][j] = MFMA_BF16(af[i][1], bfm[j][1], acc[i][j]);
                }
        }
    }

#pragma unroll
    for (int i = 0; i < 4; ++i)
#pragma unroll
        for (int j = 0; j < 4; ++j) {
            if (CMODE == 2) {
                size_t row0 = m0 + wm + i * 16 + g * 4;
                size_t col  = n0 + wn + j * 16 + fr;
                size_t addr = ((row0 >> 11) * 16 + (col >> 6)) * BHSTRIDE
                            + (size_t)(col & 63) * 2048 + (row0 & 2047);
                ushort4 pk;
                pk.x = f2bf(acc[i][j][0] * scale);
                pk.y = f2bf(acc[i][j][1] * scale);
                pk.z = f2bf(acc[i][j][2] * scale);
                pk.w = f2bf(acc[i][j][3] * scale);
                *(ushort4*)((u16*)Cv + addr) = pk;
            } else {
#pragma unroll
                for (int rg = 0; rg < 4; ++rg) {
                    size_t row = m0 + wm + i * 16 + g * 4 + rg;
                    size_t col = n0 + wn + j * 16 + fr;
                    float v = acc[i][j][rg] * scale;
                    if (CMODE == 0) {
                        ((float*)Cv)[row * 1024 + col] = v;
                    } else {
                        size_t addr = ((row >> 11) * 16 + (col >> 6)) * BHSTRIDE
                                    + (row & 2047) * 64 + (col & 63);
                        ((u16*)Cv)[addr] = f2bf(v);
                    }
                }
            }
        }
}

// ---------------------------------------------------------------------------
// Flash attention (identical to R10/R11): 32x32x16 MFMA, swapped QK^T,
// in-register P, fenced 2-state pipeline over TWO q-tiles per wave.
// ---------------------------------------------------------------------------
__global__ __launch_bounds__(256, 2) void flash_kernel(
    const u16* __restrict__ Qhm, const u16* __restrict__ Khm,
    const u16* __restrict__ Vt, u16* __restrict__ Ohm)
{
    __shared__ __align__(16) u16 sK[2][128 * 64];    // 32 KB
    __shared__ __align__(16) u16 sVt[2][64 * 128];   // 32 KB

    const int tid  = threadIdx.x;
    const int lane = tid & 63;
    const int wave = tid >> 6;            // 0..3
    const int l31  = lane & 31;
    const int hg   = lane >> 5;

    const int lin  = blockIdx.x;          // 0..511
    const int slot = lin >> 3;            // 0..63
    const int bh   = (lin & 7) + 8 * (slot >> 3);
    const int q0   = (slot & 7) * 256;

    const u16* Qh = Qhm + (size_t)bh * BHSTRIDE;
    const u16* Kh = Khm + (size_t)bh * BHSTRIDE;
    const u16* Vh = Vt  + (size_t)bh * BHSTRIDE;
    u16*       Oh = Ohm + (size_t)bh * BHSTRIDE;

    bf16x8 qbf[2][4];
#pragma unroll
    for (int qt = 0; qt < 2; ++qt)
#pragma unroll
        for (int dc = 0; dc < 4; ++dc)
            qbf[qt][dc] = *(const bf16x8*)(Qh +
                (size_t)(q0 + wave * 64 + qt * 32 + l31) * 64 + dc * 16 + hg * 8);

    f32x16 oaccA[2] = {};
    f32x16 oaccB[2] = {};
    float lsA[2] = {}, lsB[2] = {};

    const int krow8 = tid >> 3, kcp = tid & 7;
    const int vd16  = tid >> 4, vcp = tid & 15;

    auto stage = [&](int buf, int kt) {
#pragma unroll
        for (int it = 0; it < 4; ++it) {
            int row = it * 32 + krow8;
            int sc = kcp ^ (((row >> 3) ^ row) & 7);
            async_copy16(Kh + (size_t)(kt * 128 + row) * 64 + sc * 8,
                         (char*)(&sK[buf][0]) + it * 4096 + tid * 16);
        }
#pragma unroll
        for (int it = 0; it < 4; ++it) {
            int d = it * 16 + vd16;
            int sc = vcp ^ (d & 15);
            async_copy16(Vh + (size_t)d * 2048 + kt * 128 + sc * 8,
                         (char*)(&sVt[buf][0]) + it * 4096 + tid * 16);
        }
    };

    auto qk2 = [&](const u16* sKc, int kc, f32x16& sa0, f32x16& sa1) {
        sa0 = (f32x16){};
        sa1 = (f32x16){};
        const int krow = kc * 32 + l31;
        const int ksw = ((krow >> 3) ^ krow) & 7;
#pragma unroll
        for (int dc = 0; dc < 4; ++dc) {
            bf16x8 ka = *(const bf16x8*)(sKc + krow * 64 + ((dc * 2 + hg) ^ ksw) * 8);
            sa0 = MFMA32(ka, qbf[0][dc], sa0);
            sa1 = MFMA32(ka, qbf[1][dc], sa1);
        }
    };

    auto sm = [&](const f32x16& sa, bf16x8& o0, bf16x8& o1, float* ls) {
        float p[16];
#pragma unroll
        for (int r = 0; r < 16; ++r) p[r] = aexp2(sa[r]);
#pragma unroll
        for (int r = 0; r < 16; ++r) ls[r & 1] += p[r];
        uint32_t w0 = cvtpk(p[0],  p[1]),  w1 = cvtpk(p[2],  p[3]);
        uint32_t w2 = cvtpk(p[4],  p[5]),  w3 = cvtpk(p[6],  p[7]);
        uint32_t w4 = cvtpk(p[8],  p[9]),  w5 = cvtpk(p[10], p[11]);
        uint32_t w6 = cvtpk(p[12], p[13]), w7 = cvtpk(p[14], p[15]);
        plswap(w0, w2); plswap(w1, w3);
        plswap(w4, w6); plswap(w5, w7);
        o0 = mkfrag(w0, w1, w2, w3);
        o1 = mkfrag(w4, w5, w6, w7);
    };

    auto pv2 = [&](const u16* sVc, int kc, bf16x8 a0, bf16x8 a1,
                   bf16x8 b0, bf16x8 b1) {
        bf16x8 vb[2][2];
#pragma unroll
        for (int sub = 0; sub < 2; ++sub)
#pragma unroll
            for (int dt = 0; dt < 2; ++dt) {
                int dr = dt * 32 + l31;
                vb[sub][dt] = *(const bf16x8*)(sVc + dr * 128 +
                    ((kc * 4 + sub * 2 + hg) ^ (dr & 15)) * 8);
            }
        oaccA[0] = MFMA32(a0, vb[0][0], oaccA[0]);
        oaccA[1] = MFMA32(a0, vb[0][1], oaccA[1]);
        oaccB[0] = MFMA32(b0, vb[0][0], oaccB[0]);
        oaccB[1] = MFMA32(b0, vb[0][1], oaccB[1]);
        oaccA[0] = MFMA32(a1, vb[1][0], oaccA[0]);
        oaccA[1] = MFMA32(a1, vb[1][1], oaccA[1]);
        oaccB[0] = MFMA32(b1, vb[1][0], oaccB[0]);
        oaccB[1] = MFMA32(b1, vb[1][1], oaccB[1]);
    };

    stage(0, 0);
    __syncthreads();

    int cur = 0;
    for (int kt = 0; kt < 16; ++kt) {
        const u16* sKc = &sK[cur][0];
        const u16* sVc = &sVt[cur][0];

        f32x16 sA, sB, nA, nB;
        qk2(sKc, 0, sA, sB);
        if (kt < 15) stage(cur ^ 1, kt + 1);
        FENCE();

        bf16x8 a0, a1, b0, b1;
        sm(sA, a0, a1, lsA);   FENCE();
        qk2(sKc, 1, nA, nB);   FENCE();
        sm(sB, b0, b1, lsB);   FENCE();
        pv2(sVc, 0, a0, a1, b0, b1); FENCE();
        sm(nA, a0, a1, lsA);   FENCE();
        qk2(sKc, 2, sA, sB);   FENCE();
        sm(nB, b0, b1, lsB);   FENCE();
        pv2(sVc, 1, a0, a1, b0, b1); FENCE();
        sm(sA, a0, a1, lsA);   FENCE();
        qk2(sKc, 3, nA, nB);   FENCE();
        sm(sB, b0, b1, lsB);   FENCE();
        pv2(sVc, 2, a0, a1, b0, b1); FENCE();
        sm(nA, a0, a1, lsA);   FENCE();
        sm(nB, b0, b1, lsB);   FENCE();
        pv2(sVc, 3, a0, a1, b0, b1);

        __syncthreads();
        cur ^= 1;
    }

#pragma unroll
    for (int qt = 0; qt < 2; ++qt) {
        float l = qt ? (lsB[0] + lsB[1]) : (lsA[0] + lsA[1]);
        l += __shfl_xor(l, 32);
        float inv = 1.0f / l;
        const f32x16* oa = qt ? oaccB : oaccA;
#pragma unroll
        for (int r = 0; r < 16; ++r) {
            int row = (r & 3) + 4 * hg + 8 * (r >> 2);
            float invr = __shfl(inv, row);
            size_t grow = (size_t)q0 + wave * 64 + qt * 32 + row;
            Oh[grow * 64 + l31]      = f2bf(oa[0][r] * invr);
            Oh[grow * 64 + 32 + l31] = f2bf(oa[1][r] * invr);
        }
    }
}

// ---------------------------------------------------------------------------
extern "C" void kernel_launch(void* const* d_in, const int* in_sizes, int n_in,
                              void* d_out, int out_size, void* d_ws, size_t ws_size,
                              hipStream_t stream)
{
    const float* X    = (const float*)d_in[0];
    const float* R    = (const float*)d_in[1];
    const float* E    = (const float*)d_in[2];
    const float* Wq   = (const float*)d_in[3];
    const float* Wk   = (const float*)d_in[4];
    const float* Wv   = (const float*)d_in[5];
    const float* Wrot = (const float*)d_in[6];
    const float* Went = (const float*)d_in[7];
    const float* Wo   = (const float*)d_in[8];

    const size_t NT = 8192 * 1024;
    const size_t NW = 1024 * 1024;

    // d_out doubles as scratch for Qhm/Khm (bf16, head-major).
    u16* Qhm = (u16*)d_out;
    u16* Khm = Qhm + NT;
    // ws: Xb | Rb->(Vt fallback) | Eb->Ohm | 6 bf16 weights | [VtX if room]
    u16* Xb  = (u16*)d_ws;
    u16* RVb = Xb + NT;
    u16* EOb = RVb + NT;
    u16* Wqb = EOb + NT;
    u16* Wkb   = Wqb + NW;
    u16* Wvb   = Wkb + NW;
    u16* Wrotb = Wvb + NW;
    u16* Wentb = Wrotb + NW;
    u16* Wob   = Wentb + NW;
    u16* VtX   = Wob + NW;      // needs ws_size >= (4*NT + 6*NW) * 2 bytes

    const bool bigws = ws_size >= (4 * NT + 6 * NW) * sizeof(u16);
    u16* Vt = bigws ? VtX : RVb;

    {   // all conversions in one launch
        CvtArgs a{};
        a.s[0] = X;  a.s[1] = R;  a.s[2] = E;
        a.s[3] = Wq; a.s[4] = Wk; a.s[5] = Wv;
        a.s[6] = Wrot; a.s[7] = Went; a.s[8] = Wo;
        a.d[0] = Xb;  a.d[1] = RVb;  a.d[2] = EOb;
        a.d[3] = Wqb; a.d[4] = Wkb;  a.d[5] = Wvb;
        a.d[6] = Wrotb; a.d[7] = Wentb; a.d[8] = Wob;
        cvt_kernel<<<dim3(4096, 1, 9), 256, 0, stream>>>(a);
    }

    if (bigws) {
        // Q, K, V projections fused: 1536 blocks, 5 blocks/CU (LDS cap).
        qkv_proj<<<dim3(64, 24), 256, 0, stream>>>(Xb, Wqb, RVb, Wrotb, Qhm,
                                                   Wkb, EOb, Wentb, Khm,
                                                   Wvb, VtX);
    } else {
        qk_proj<<<dim3(64, 16), 256, 0, stream>>>(Xb, Wqb, RVb, Wrotb, Qhm,
                                                  Wkb, EOb, Wentb, Khm);
        gemm_bt<0, 2><<<dim3(64, 8), 256, 0, stream>>>(Xb, Wvb, nullptr, nullptr,
                                                       RVb, 1024, 1, 1.0f);
    }
    flash_kernel<<<dim3(512), 256, 0, stream>>>(Qhm, Khm, Vt, EOb);
    gemm_bt<1, 0><<<dim3(64, 8), 256, 0, stream>>>(EOb, Wob, nullptr, nullptr,
                                                   d_out, 1024, 1, 1.0f);
}